// Round 10
// baseline (886.936 us; speedup 1.0000x reference)
//
#include <hip/hip_runtime.h>
#include <hip/hip_bf16.h>

typedef unsigned short ushort_t;
typedef __attribute__((ext_vector_type(8))) short short8;
typedef __attribute__((ext_vector_type(4))) float f32x4;
typedef __attribute__((ext_vector_type(4))) unsigned int uint4v;

#define NQ      2048
#define ND      512
#define NDB     100000
#define TOPK    10
#define NS      98                    // n-slices
#define SLICE   1024                  // db rows per slice
#define NF      (SLICE / 16)          // 64 16-row tiles per slice
#define NPAD    (NS * SLICE)          // 100352 >= 100000
#define NQG     16                    // q-groups of 128
#define NWG     (NS * NQG)            // 1568 = 8 * 196
#define PERXCD  (NWG / 8)             // 196

// ---------- fp32 -> bf16 (round to nearest even) ----------
static __device__ inline ushort_t f2bf(float x) {
    unsigned u = __float_as_uint(x);
    unsigned r = (u + 0x7FFFu + ((u >> 16) & 1u)) >> 16;
    return (ushort_t)r;
}

// ---------- row L2-normalize, fp32 -> bf16; zero-fill pad rows ----------
__global__ void normalize_rows(const float* __restrict__ in, ushort_t* __restrict__ out,
                               int nvalid, int ntotal) {
    int row  = blockIdx.x * 4 + (threadIdx.x >> 6);
    int lane = threadIdx.x & 63;
    if (row >= ntotal) return;
    uint4v pk;
    if (row >= nvalid) {
        pk[0] = 0u; pk[1] = 0u; pk[2] = 0u; pk[3] = 0u;
    } else {
        const float4* src = reinterpret_cast<const float4*>(in + (size_t)row * ND);
        float4 v0 = src[lane * 2];
        float4 v1 = src[lane * 2 + 1];
        float s = v0.x*v0.x + v0.y*v0.y + v0.z*v0.z + v0.w*v0.w
                + v1.x*v1.x + v1.y*v1.y + v1.z*v1.z + v1.w*v1.w;
        #pragma unroll
        for (int off = 32; off; off >>= 1) s += __shfl_xor(s, off, 64);
        float r = rsqrtf(s);
        pk[0] = (unsigned)f2bf(v0.x * r) | ((unsigned)f2bf(v0.y * r) << 16);
        pk[1] = (unsigned)f2bf(v0.z * r) | ((unsigned)f2bf(v0.w * r) << 16);
        pk[2] = (unsigned)f2bf(v1.x * r) | ((unsigned)f2bf(v1.y * r) << 16);
        pk[3] = (unsigned)f2bf(v1.z * r) | ((unsigned)f2bf(v1.w * r) << 16);
    }
    *reinterpret_cast<uint4v*>(out + (size_t)row * ND + lane * 8) = pk;
}

__device__ inline void topk_insert(float (&top)[TOPK], float x) {
    #pragma unroll
    for (int i = 0; i < TOPK; ++i) {
        float mx = fmaxf(top[i], x);
        x = fminf(top[i], x);
        top[i] = mx;
    }
}

// ---------- reg-streaming GEMM + top-10: NO LDS, NO per-step barriers ----------
// 256 threads, 4 waves (1/SIMD). Wave wv owns q-range [qg*128+wv*32, +32); the
// block's 4 waves stream the SAME 1024-row n-slice (B served by L1/L2, db is
// L2/L3-resident). Per 16-row nf-tile: 16 global b128 B-loads feed 32 MFMA,
// software-pipelined one tile ahead (issue after use, ~350 cyc cover). Sync is
// compiler-inserted counted vmcnt only; one skew-bounding s_barrier per 8 nf.
// SWAPPED mfma(B,A): thread (l15,lhi) holds q = qs*16+l15, n = nb + lhi*4 + r.
__global__ __launch_bounds__(256, 2)
void knn_stream(const ushort_t* __restrict__ qb, const ushort_t* __restrict__ dbb,
                float* __restrict__ partial) {
    const int logical = (blockIdx.x & 7) * PERXCD + (blockIdx.x >> 3);
    const int ns = logical >> 4;          // 0..97  (16 consecutive logicals share a slice)
    const int qg = logical & 15;          // 0..15
    const int lane = threadIdx.x & 63, wv = threadIdx.x >> 6;
    const int l15 = lane & 15, lhi = lane >> 4;

    // ---- A panel: wave's 32 q rows x K=512 in registers (MFMA B-operand layout:
    // col(q) = lane&15, k = (lane>>4)*8 + j within each 32-k slice kk)
    short8 af[2][16];
    {
        const ushort_t* ap = qb + (size_t)(qg * 128 + wv * 32 + l15) * ND + lhi * 8;
        #pragma unroll
        for (int qs = 0; qs < 2; ++qs)
            #pragma unroll
            for (int kk = 0; kk < 16; ++kk)
                af[qs][kk] = *reinterpret_cast<const short8*>(ap + qs * 16 * ND + kk * 32);
    }

    float top[2][TOPK];
    #pragma unroll
    for (int qs = 0; qs < 2; ++qs)
        #pragma unroll
        for (int i = 0; i < TOPK; ++i) top[qs][i] = -1e30f;

    // B stream pointer: lane covers row nb + l15, k-chunk lhi*8 (A-operand layout)
    const ushort_t* bp = dbb + (size_t)(ns * SLICE + l15) * ND + lhi * 8;

    // prologue: tile 0 fully issued
    short8 curA[8], curB[8];
    #pragma unroll
    for (int kk = 0; kk < 8; ++kk)
        curA[kk] = *reinterpret_cast<const short8*>(bp + kk * 32);
    #pragma unroll
    for (int kk = 0; kk < 8; ++kk)
        curB[kk] = *reinterpret_cast<const short8*>(bp + 256 + kk * 32);

    #pragma unroll 1
    for (int nf = 0; nf < NF; ++nf) {
        // next-tile pointer; at the last tile this runs 16 KB past the slice —
        // still inside the workspace (qbn follows dbb), loaded but never used.
        const ushort_t* bpn = bp + 16 * ND;
        f32x4 acc0 = (f32x4){0.f, 0.f, 0.f, 0.f};
        f32x4 acc1 = (f32x4){0.f, 0.f, 0.f, 0.f};

        // phase A: k 0..255 (compiler waits on curA only; curB still in flight)
        #pragma unroll
        for (int kk = 0; kk < 8; ++kk) {
            acc0 = __builtin_amdgcn_mfma_f32_16x16x32_bf16(curA[kk], af[0][kk], acc0, 0, 0, 0);
            acc1 = __builtin_amdgcn_mfma_f32_16x16x32_bf16(curA[kk], af[1][kk], acc1, 0, 0, 0);
        }
        // reissue curA for next tile (WAR on regs just consumed)
        #pragma unroll
        for (int kk = 0; kk < 8; ++kk)
            curA[kk] = *reinterpret_cast<const short8*>(bpn + kk * 32);

        // phase B: k 256..511
        #pragma unroll
        for (int kk = 0; kk < 8; ++kk) {
            acc0 = __builtin_amdgcn_mfma_f32_16x16x32_bf16(curB[kk], af[0][kk + 8], acc0, 0, 0, 0);
            acc1 = __builtin_amdgcn_mfma_f32_16x16x32_bf16(curB[kk], af[1][kk + 8], acc1, 0, 0, 0);
        }
        #pragma unroll
        for (int kk = 0; kk < 8; ++kk)
            curB[kk] = *reinterpret_cast<const short8*>(bpn + 256 + kk * 32);

        // selection: this thread's 4 n-candidates per qs (n = nb + lhi*4 + r)
        {
            float m0 = fmaxf(fmaxf(acc0[0], acc0[1]), fmaxf(acc0[2], acc0[3]));
            if (m0 > top[0][TOPK - 1]) {
                #pragma unroll
                for (int r = 0; r < 4; ++r)
                    if (acc0[r] > top[0][TOPK - 1]) topk_insert(top[0], acc0[r]);
            }
            float m1 = fmaxf(fmaxf(acc1[0], acc1[1]), fmaxf(acc1[2], acc1[3]));
            if (m1 > top[1][TOPK - 1]) {
                #pragma unroll
                for (int r = 0; r < 4; ++r)
                    if (acc1[r] > top[1][TOPK - 1]) topk_insert(top[1], acc1[r]);
            }
        }

        bp = bpn;
        if ((nf & 7) == 7) __builtin_amdgcn_s_barrier();   // bound wave skew for L1 reuse
    }

    // butterfly merge across the 4 lanes sharing each query (lane ^ 16, lane ^ 32)
    #pragma unroll
    for (int qs = 0; qs < 2; ++qs) {
        #pragma unroll
        for (int step = 16; step <= 32; step <<= 1) {
            float other[TOPK];
            #pragma unroll
            for (int i = 0; i < TOPK; ++i) other[i] = __shfl_xor(top[qs][i], step, 64);
            #pragma unroll
            for (int i = 0; i < TOPK; ++i)
                if (other[i] > top[qs][TOPK - 1]) topk_insert(top[qs], other[i]);
        }
    }

    // lanes 0..15 hold the per-slice top-10 for q = qg*128 + wv*32 + qs*16 + l15
    if (lhi == 0) {
        #pragma unroll
        for (int qs = 0; qs < 2; ++qs) {
            const int q = qg * 128 + wv * 32 + qs * 16 + l15;
            float* dst = partial + ((size_t)ns * NQ + q) * TOPK;
            #pragma unroll
            for (int i = 0; i < TOPK; ++i) dst[i] = top[qs][i];
        }
    }
}

// ---------- merge NS slices per query: one wave per query ----------
__global__ void final_merge(const float* __restrict__ partial, float* __restrict__ out) {
    const int q = blockIdx.x * 4 + (threadIdx.x >> 6);
    const int lane = threadIdx.x & 63;
    if (q >= NQ) return;
    float top[TOPK];
    #pragma unroll
    for (int i = 0; i < TOPK; ++i) top[i] = -1e30f;
    for (int c = lane; c < NS; c += 64) {
        const float* p = partial + ((size_t)c * NQ + q) * TOPK;
        #pragma unroll
        for (int i = 0; i < TOPK; ++i) {
            float x = p[i];
            if (x > top[TOPK - 1]) topk_insert(top, x);
        }
    }
    #pragma unroll
    for (int step = 1; step <= 32; step <<= 1) {
        float other[TOPK];
        #pragma unroll
        for (int i = 0; i < TOPK; ++i) other[i] = __shfl_xor(top[i], step, 64);
        #pragma unroll
        for (int i = 0; i < TOPK; ++i)
            if (other[i] > top[TOPK - 1]) topk_insert(top, other[i]);
    }
    if (lane == 0) out[q] = 2.0f - 2.0f * top[TOPK - 1];
}

extern "C" void kernel_launch(void* const* d_in, const int* in_sizes, int n_in,
                              void* d_out, int out_size, void* d_ws, size_t ws_size,
                              hipStream_t stream) {
    const float* features = (const float*)d_in[0];
    const float* dbf      = (const float*)d_in[2];
    float* out = (float*)d_out;

    ushort_t* dbb = (ushort_t*)d_ws;                         // [NPAD][512] bf16   ~102.8 MB
    ushort_t* qbn = dbb + (size_t)NPAD * ND;                 // [2048][512] bf16   ~2 MB
    float* partial = (float*)(qbn + (size_t)NQ * ND);        // [NS][2048][10]     ~8.0 MB

    normalize_rows<<<NPAD / 4, 256, 0, stream>>>(dbf, dbb, NDB, NPAD);
    normalize_rows<<<NQ / 4, 256, 0, stream>>>(features, qbn, NQ, NQ);
    knn_stream<<<NWG, 256, 0, stream>>>(qbn, dbb, partial);
    final_merge<<<NQ / 4, 256, 0, stream>>>(partial, out);
}

// Round 11
// 462.655 us; speedup vs baseline: 1.9171x; 1.9171x over previous
//
#include <hip/hip_runtime.h>
#include <hip/hip_bf16.h>

typedef unsigned short ushort_t;
typedef __attribute__((ext_vector_type(8))) short short8;
typedef __attribute__((ext_vector_type(4))) float f32x4;
typedef __attribute__((ext_vector_type(4))) unsigned int uint4v;

#define NQ      2048
#define ND      512
#define NDB     100000
#define TOPK    10
#define NCHUNK  98
#define CHUNK_N 1024                  // 8 tiles * 128
#define NPAD    (NCHUNK * CHUNK_N)    // 100352 >= 100000
#define QTILES  (NQ / 128)            // 16
#define NTILES  (CHUNK_N / 128)       // 8
#define NWG     (NCHUNK * QTILES)     // 1568 = 8 * 196
#define PERXCD  (NWG / 8)             // 196

// async global->LDS, 16B per lane, wave-uniform LDS base + lane*16
#define GL2LDS(gp, lp) __builtin_amdgcn_global_load_lds(                      \
    (const __attribute__((address_space(1))) void*)(gp),                     \
    (__attribute__((address_space(3))) void*)(lp), 16, 0, 0)

// ---------- fp32 -> bf16 (round to nearest even) ----------
static __device__ inline ushort_t f2bf(float x) {
    unsigned u = __float_as_uint(x);
    unsigned r = (u + 0x7FFFu + ((u >> 16) & 1u)) >> 16;
    return (ushort_t)r;
}

// ---------- row L2-normalize, fp32 -> bf16; zero-fill pad rows ----------
__global__ void normalize_rows(const float* __restrict__ in, ushort_t* __restrict__ out,
                               int nvalid, int ntotal) {
    int row  = blockIdx.x * 4 + (threadIdx.x >> 6);
    int lane = threadIdx.x & 63;
    if (row >= ntotal) return;
    uint4v pk;
    if (row >= nvalid) {
        pk[0] = 0u; pk[1] = 0u; pk[2] = 0u; pk[3] = 0u;
    } else {
        const float4* src = reinterpret_cast<const float4*>(in + (size_t)row * ND);
        float4 v0 = src[lane * 2];
        float4 v1 = src[lane * 2 + 1];
        float s = v0.x*v0.x + v0.y*v0.y + v0.z*v0.z + v0.w*v0.w
                + v1.x*v1.x + v1.y*v1.y + v1.z*v1.z + v1.w*v1.w;
        #pragma unroll
        for (int off = 32; off; off >>= 1) s += __shfl_xor(s, off, 64);
        float r = rsqrtf(s);
        pk[0] = (unsigned)f2bf(v0.x * r) | ((unsigned)f2bf(v0.y * r) << 16);
        pk[1] = (unsigned)f2bf(v0.z * r) | ((unsigned)f2bf(v0.w * r) << 16);
        pk[2] = (unsigned)f2bf(v1.x * r) | ((unsigned)f2bf(v1.y * r) << 16);
        pk[3] = (unsigned)f2bf(v1.z * r) | ((unsigned)f2bf(v1.w * r) << 16);
    }
    *reinterpret_cast<uint4v*>(out + (size_t)row * ND + lane * 8) = pk;
}

__device__ inline void topk_insert(float (&top)[TOPK], float x) {
    #pragma unroll
    for (int i = 0; i < TOPK; ++i) {
        float mx = fmaxf(top[i], x);
        x = fminf(top[i], x);
        top[i] = mx;
    }
}

// ---------- fused GEMM + per-chunk top-10 (R4 structure, 4 blocks/CU) ----------
// 256 threads, 4 waves; wave wv owns queries [wv*32, +32) x all 128 n of the tile.
// A+B staged to LDS via gl2lds (both-sides XOR swizzle, 0-conflict reads).
// SWAPPED mfma(B,A): acc[qs][ns][r] = score[n][q = qs*16+(lane&15)] -> top-10 in regs.
// No A/B register panels (that spilled in R5-R7); VGPR ~80 -> 4 blocks/CU.
__global__ __launch_bounds__(256, 4)
void knn_chunk(const ushort_t* __restrict__ qb, const ushort_t* __restrict__ dbb,
               float* __restrict__ partial) {
    // XCD swizzle: 16 consecutive logicals (same B-chunk) land on the same XCD
    const int logical = (blockIdx.x & 7) * PERXCD + (blockIdx.x >> 3);
    const int qt = logical & (QTILES - 1);
    const int nc = logical >> 4;       // QTILES == 16
    const int t = threadIdx.x, lane = t & 63, wv = t >> 6;

    __shared__ __align__(16) ushort_t As[128 * 64];
    __shared__ __align__(16) ushort_t Bs[128 * 64];

    float top[2][TOPK];
    #pragma unroll
    for (int qs = 0; qs < 2; ++qs)
        #pragma unroll
        for (int i = 0; i < TOPK; ++i) top[qs][i] = -1e30f;

    const size_t nchunkbase = (size_t)nc * CHUNK_N;
    const int cb = wv * 256;                 // wave's 16B-chunk base (1024 chunks/tile)
    const ushort_t* aseg = qb + (size_t)(qt * 128) * ND;

    for (int nt = 0; nt < NTILES; ++nt) {
        const ushort_t* bseg = dbb + (nchunkbase + nt * 128) * ND;
        f32x4 acc[2][8];
        #pragma unroll
        for (int a = 0; a < 2; ++a)
            #pragma unroll
            for (int b = 0; b < 8; ++b)
                acc[a][b] = (f32x4){0.f, 0.f, 0.f, 0.f};

        #pragma unroll 1
        for (int ks = 0; ks < 8; ++ks) {
            const int kbase = ks * 64;
            __syncthreads();   // previous sub-tile's frags consumed
            #pragma unroll
            for (int i = 0; i < 4; ++i) {
                const int cid = cb + i * 64 + lane;       // this lane's chunk
                const int row = cid >> 3;
                const int c   = (cid & 7) ^ (row & 7);    // inverse swizzle on global source
                const size_t go = (size_t)row * ND + kbase + c * 8;
                GL2LDS(aseg + go, As + (cb + i * 64) * 8);
                GL2LDS(bseg + go, Bs + (cb + i * 64) * 8);
            }
            __syncthreads();   // tile staged
            #pragma unroll
            for (int ksub = 0; ksub < 2; ++ksub) {
                const int cgrp = ksub * 4 + (lane >> 4);  // logical 16B chunk in row
                short8 af[2], bf[8];
                #pragma unroll
                for (int qs = 0; qs < 2; ++qs) {
                    const int ar = wv * 32 + qs * 16 + (lane & 15);
                    af[qs] = *reinterpret_cast<const short8*>(As + ar * 64 + ((cgrp ^ (ar & 7)) * 8));
                }
                #pragma unroll
                for (int ns = 0; ns < 8; ++ns) {
                    const int br = ns * 16 + (lane & 15);
                    bf[ns] = *reinterpret_cast<const short8*>(Bs + br * 64 + ((cgrp ^ (br & 7)) * 8));
                }
                #pragma unroll
                for (int qs = 0; qs < 2; ++qs)
                    #pragma unroll
                    for (int ns = 0; ns < 8; ++ns)
                        acc[qs][ns] = __builtin_amdgcn_mfma_f32_16x16x32_bf16(bf[ns], af[qs], acc[qs][ns], 0, 0, 0);
            }
        }

        // in-register selection: per qs, 32 candidates for this thread's fixed query
        #pragma unroll
        for (int qs = 0; qs < 2; ++qs) {
            float m = -1e30f;
            #pragma unroll
            for (int ns = 0; ns < 8; ++ns) {
                float m0 = fmaxf(fmaxf(acc[qs][ns][0], acc[qs][ns][1]),
                                 fmaxf(acc[qs][ns][2], acc[qs][ns][3]));
                m = fmaxf(m, m0);
            }
            if (m > top[qs][TOPK - 1]) {
                #pragma unroll
                for (int ns = 0; ns < 8; ++ns)
                    #pragma unroll
                    for (int r = 0; r < 4; ++r) {
                        float v = acc[qs][ns][r];
                        if (v > top[qs][TOPK - 1]) topk_insert(top[qs], v);
                    }
            }
        }
    }

    // butterfly merge across the 4 lanes sharing each query (lane ^ 16, lane ^ 32)
    #pragma unroll
    for (int qs = 0; qs < 2; ++qs) {
        #pragma unroll
        for (int step = 16; step <= 32; step <<= 1) {
            float other[TOPK];
            #pragma unroll
            for (int i = 0; i < TOPK; ++i) other[i] = __shfl_xor(top[qs][i], step, 64);
            #pragma unroll
            for (int i = 0; i < TOPK; ++i)
                if (other[i] > top[qs][TOPK - 1]) topk_insert(top[qs], other[i]);
        }
    }

    // lanes 0..15 hold the final per-query top-10 for q = qt*128 + wv*32 + qs*16 + lane
    if ((lane >> 4) == 0) {
        #pragma unroll
        for (int qs = 0; qs < 2; ++qs) {
            const int q = qt * 128 + wv * 32 + qs * 16 + lane;
            float* dst = partial + ((size_t)nc * NQ + q) * TOPK;
            #pragma unroll
            for (int i = 0; i < TOPK; ++i) dst[i] = top[qs][i];
        }
    }
}

// ---------- merge NCHUNK chunks per query: one wave per query ----------
__global__ void final_merge(const float* __restrict__ partial, float* __restrict__ out) {
    const int q = blockIdx.x * 4 + (threadIdx.x >> 6);
    const int lane = threadIdx.x & 63;
    if (q >= NQ) return;
    float top[TOPK];
    #pragma unroll
    for (int i = 0; i < TOPK; ++i) top[i] = -1e30f;
    for (int c = lane; c < NCHUNK; c += 64) {
        const float* p = partial + ((size_t)c * NQ + q) * TOPK;
        #pragma unroll
        for (int i = 0; i < TOPK; ++i) {
            float x = p[i];
            if (x > top[TOPK - 1]) topk_insert(top, x);
        }
    }
    #pragma unroll
    for (int step = 1; step <= 32; step <<= 1) {
        float other[TOPK];
        #pragma unroll
        for (int i = 0; i < TOPK; ++i) other[i] = __shfl_xor(top[i], step, 64);
        #pragma unroll
        for (int i = 0; i < TOPK; ++i)
            if (other[i] > top[TOPK - 1]) topk_insert(top, other[i]);
    }
    if (lane == 0) out[q] = 2.0f - 2.0f * top[TOPK - 1];
}

extern "C" void kernel_launch(void* const* d_in, const int* in_sizes, int n_in,
                              void* d_out, int out_size, void* d_ws, size_t ws_size,
                              hipStream_t stream) {
    const float* features = (const float*)d_in[0];
    const float* dbf      = (const float*)d_in[2];
    float* out = (float*)d_out;

    ushort_t* dbb = (ushort_t*)d_ws;                         // [NPAD][512] bf16   ~102.8 MB
    ushort_t* qbn = dbb + (size_t)NPAD * ND;                 // [2048][512] bf16   ~2 MB
    float* partial = (float*)(qbn + (size_t)NQ * ND);        // [NCHUNK][2048][10] ~8.0 MB

    normalize_rows<<<NPAD / 4, 256, 0, stream>>>(dbf, dbb, NDB, NPAD);
    normalize_rows<<<NQ / 4, 256, 0, stream>>>(features, qbn, NQ, NQ);
    knn_chunk<<<NWG, 256, 0, stream>>>(qbn, dbb, partial);
    final_merge<<<NQ / 4, 256, 0, stream>>>(partial, out);
}

// Round 12
// 409.166 us; speedup vs baseline: 2.1677x; 1.1307x over previous
//
#include <hip/hip_runtime.h>
#include <hip/hip_bf16.h>

typedef unsigned short ushort_t;
typedef unsigned char uchar_t;
typedef __attribute__((ext_vector_type(4))) int int4v;
typedef __attribute__((ext_vector_type(4))) unsigned int uint4v;
typedef __attribute__((ext_vector_type(2))) unsigned int uint2v;

#define NQ      2048
#define ND      512
#define NDB     100000
#define TOPK    10
#define NCHUNK  98
#define CHUNK_N 1024                  // 8 tiles * 128
#define NPAD    (NCHUNK * CHUNK_N)    // 100352 >= 100000
#define QTILES  (NQ / 128)            // 16
#define NTILES  (CHUNK_N / 128)       // 8
#define NWG     (NCHUNK * QTILES)     // 1568 = 8 * 196
#define PERXCD  (NWG / 8)             // 196
#define QSCALE  400.0f
#define QINV    (1.0f / (QSCALE * QSCALE))

// async global->LDS, 16B per lane, wave-uniform LDS base + lane*16
#define GL2LDS(gp, lp) __builtin_amdgcn_global_load_lds(                      \
    (const __attribute__((address_space(1))) void*)(gp),                     \
    (__attribute__((address_space(3))) void*)(lp), 16, 0, 0)

// ---------- row L2-normalize, fp32 -> i8 (x*400, RNE, clamp +-127); zero pad rows ----------
__global__ void normalize_rows_i8(const float* __restrict__ in, uchar_t* __restrict__ out,
                                  int nvalid, int ntotal) {
    int row  = blockIdx.x * 4 + (threadIdx.x >> 6);
    int lane = threadIdx.x & 63;
    if (row >= ntotal) return;
    uint2v pk;
    if (row >= nvalid) {
        pk[0] = 0u; pk[1] = 0u;
    } else {
        const float4* src = reinterpret_cast<const float4*>(in + (size_t)row * ND);
        float4 v0 = src[lane * 2];
        float4 v1 = src[lane * 2 + 1];
        float s = v0.x*v0.x + v0.y*v0.y + v0.z*v0.z + v0.w*v0.w
                + v1.x*v1.x + v1.y*v1.y + v1.z*v1.z + v1.w*v1.w;
        #pragma unroll
        for (int off = 32; off; off >>= 1) s += __shfl_xor(s, off, 64);
        float r = rsqrtf(s) * QSCALE;
        float f[8] = { v0.x, v0.y, v0.z, v0.w, v1.x, v1.y, v1.z, v1.w };
        unsigned b[8];
        #pragma unroll
        for (int i = 0; i < 8; ++i) {
            int q = (int)rintf(f[i] * r);
            q = q > 127 ? 127 : (q < -127 ? -127 : q);
            b[i] = (unsigned)q & 0xFFu;
        }
        pk[0] = b[0] | (b[1] << 8) | (b[2] << 16) | (b[3] << 24);
        pk[1] = b[4] | (b[5] << 8) | (b[6] << 16) | (b[7] << 24);
    }
    *reinterpret_cast<uint2v*>(out + (size_t)row * ND + lane * 8) = pk;
}

__device__ inline void topk_insert(float (&top)[TOPK], float x) {
    #pragma unroll
    for (int i = 0; i < TOPK; ++i) {
        float mx = fmaxf(top[i], x);
        x = fminf(top[i], x);
        top[i] = mx;
    }
}

// ---------- fused i8 GEMM + per-chunk top-10 (R11 structure, K=128 B per step) ----------
// 256 threads, 4 waves; wave wv owns queries [wv*32, +32) x all 128 n of the tile.
// A+B staged to LDS via gl2lds (both-sides XOR swizzle; tile = 128 rows x 128 B =
// 1024 16B-chunks, IDENTICAL geometry to the proven bf16 tile). 4 K-steps of 128
// i8-k each; per K-step 2 ksub x (2 af + 8 bf b128 reads + 16 mfma_i32_16x16x64_i8).
// SWAPPED mfma(B,A): acc[qs][ns][r] = dot_i32[n][q = qs*16+(lane&15)] -> top-10 in regs.
__global__ __launch_bounds__(256, 4)
void knn_chunk(const uchar_t* __restrict__ qb, const uchar_t* __restrict__ dbb,
               float* __restrict__ partial) {
    // XCD swizzle: 16 consecutive logicals (same B-chunk) land on the same XCD
    const int logical = (blockIdx.x & 7) * PERXCD + (blockIdx.x >> 3);
    const int qt = logical & (QTILES - 1);
    const int nc = logical >> 4;       // QTILES == 16
    const int t = threadIdx.x, lane = t & 63, wv = t >> 6;

    __shared__ __align__(16) uchar_t As[128 * 128];   // 16 KB
    __shared__ __align__(16) uchar_t Bs[128 * 128];   // 16 KB

    float top[2][TOPK];
    #pragma unroll
    for (int qs = 0; qs < 2; ++qs)
        #pragma unroll
        for (int i = 0; i < TOPK; ++i) top[qs][i] = -1e30f;

    const size_t nchunkbase = (size_t)nc * CHUNK_N;
    const int cb = wv * 256;                 // wave's 16B-chunk base (1024 chunks/tile)
    const uchar_t* aseg = qb + (size_t)(qt * 128) * ND;

    for (int nt = 0; nt < NTILES; ++nt) {
        const uchar_t* bseg = dbb + (nchunkbase + nt * 128) * ND;
        int4v acc[2][8];
        #pragma unroll
        for (int a = 0; a < 2; ++a)
            #pragma unroll
            for (int b = 0; b < 8; ++b)
                acc[a][b] = (int4v){0, 0, 0, 0};

        #pragma unroll 1
        for (int ks = 0; ks < 4; ++ks) {
            const int kbase = ks * 128;            // byte offset within 512-B row
            __syncthreads();   // previous sub-tile's frags consumed
            #pragma unroll
            for (int i = 0; i < 4; ++i) {
                const int cid = cb + i * 64 + lane;       // this lane's 16B chunk
                const int row = cid >> 3;                 // 8 chunks per 128-B row
                const int c   = (cid & 7) ^ (row & 7);    // inverse swizzle on global source
                const size_t go = (size_t)row * ND + kbase + c * 16;
                GL2LDS(aseg + go, As + cid * 16);
                GL2LDS(bseg + go, Bs + cid * 16);
            }
            __syncthreads();   // tile staged
            #pragma unroll
            for (int ksub = 0; ksub < 2; ++ksub) {
                const int cgrp = ksub * 4 + (lane >> 4);  // logical 16B chunk in row
                int4v af[2], bf[8];
                #pragma unroll
                for (int qs = 0; qs < 2; ++qs) {
                    const int ar = wv * 32 + qs * 16 + (lane & 15);
                    af[qs] = *reinterpret_cast<const int4v*>(As + ar * 128 + ((cgrp ^ (ar & 7)) * 16));
                }
                #pragma unroll
                for (int ns = 0; ns < 8; ++ns) {
                    const int br = ns * 16 + (lane & 15);
                    bf[ns] = *reinterpret_cast<const int4v*>(Bs + br * 128 + ((cgrp ^ (br & 7)) * 16));
                }
                #pragma unroll
                for (int qs = 0; qs < 2; ++qs)
                    #pragma unroll
                    for (int ns = 0; ns < 8; ++ns)
                        acc[qs][ns] = __builtin_amdgcn_mfma_i32_16x16x64_i8(bf[ns], af[qs], acc[qs][ns], 0, 0, 0);
            }
        }

        // in-register selection: per qs, 32 candidates for this thread's fixed query
        #pragma unroll
        for (int qs = 0; qs < 2; ++qs) {
            float v[8][4];
            #pragma unroll
            for (int ns = 0; ns < 8; ++ns)
                #pragma unroll
                for (int r = 0; r < 4; ++r)
                    v[ns][r] = (float)acc[qs][ns][r] * QINV;
            float m = -1e30f;
            #pragma unroll
            for (int ns = 0; ns < 8; ++ns) {
                float m0 = fmaxf(fmaxf(v[ns][0], v[ns][1]), fmaxf(v[ns][2], v[ns][3]));
                m = fmaxf(m, m0);
            }
            if (m > top[qs][TOPK - 1]) {
                #pragma unroll
                for (int ns = 0; ns < 8; ++ns)
                    #pragma unroll
                    for (int r = 0; r < 4; ++r)
                        if (v[ns][r] > top[qs][TOPK - 1]) topk_insert(top[qs], v[ns][r]);
            }
        }
    }

    // butterfly merge across the 4 lanes sharing each query (lane ^ 16, lane ^ 32)
    #pragma unroll
    for (int qs = 0; qs < 2; ++qs) {
        #pragma unroll
        for (int step = 16; step <= 32; step <<= 1) {
            float other[TOPK];
            #pragma unroll
            for (int i = 0; i < TOPK; ++i) other[i] = __shfl_xor(top[qs][i], step, 64);
            #pragma unroll
            for (int i = 0; i < TOPK; ++i)
                if (other[i] > top[qs][TOPK - 1]) topk_insert(top[qs], other[i]);
        }
    }

    // lanes 0..15 hold the final per-query top-10 for q = qt*128 + wv*32 + qs*16 + lane
    if ((lane >> 4) == 0) {
        #pragma unroll
        for (int qs = 0; qs < 2; ++qs) {
            const int q = qt * 128 + wv * 32 + qs * 16 + lane;
            float* dst = partial + ((size_t)nc * NQ + q) * TOPK;
            #pragma unroll
            for (int i = 0; i < TOPK; ++i) dst[i] = top[qs][i];
        }
    }
}

// ---------- merge NCHUNK chunks per query: one wave per query ----------
__global__ void final_merge(const float* __restrict__ partial, float* __restrict__ out) {
    const int q = blockIdx.x * 4 + (threadIdx.x >> 6);
    const int lane = threadIdx.x & 63;
    if (q >= NQ) return;
    float top[TOPK];
    #pragma unroll
    for (int i = 0; i < TOPK; ++i) top[i] = -1e30f;
    for (int c = lane; c < NCHUNK; c += 64) {
        const float* p = partial + ((size_t)c * NQ + q) * TOPK;
        #pragma unroll
        for (int i = 0; i < TOPK; ++i) {
            float x = p[i];
            if (x > top[TOPK - 1]) topk_insert(top, x);
        }
    }
    #pragma unroll
    for (int step = 1; step <= 32; step <<= 1) {
        float other[TOPK];
        #pragma unroll
        for (int i = 0; i < TOPK; ++i) other[i] = __shfl_xor(top[i], step, 64);
        #pragma unroll
        for (int i = 0; i < TOPK; ++i)
            if (other[i] > top[TOPK - 1]) topk_insert(top, other[i]);
    }
    if (lane == 0) out[q] = 2.0f - 2.0f * top[TOPK - 1];
}

extern "C" void kernel_launch(void* const* d_in, const int* in_sizes, int n_in,
                              void* d_out, int out_size, void* d_ws, size_t ws_size,
                              hipStream_t stream) {
    const float* features = (const float*)d_in[0];
    const float* dbf      = (const float*)d_in[2];
    float* out = (float*)d_out;

    uchar_t* dbb = (uchar_t*)d_ws;                           // [NPAD][512] i8     ~51.4 MB
    uchar_t* qbn = dbb + (size_t)NPAD * ND;                  // [2048][512] i8     ~1 MB
    float* partial = (float*)(qbn + (size_t)NQ * ND);        // [NCHUNK][2048][10] ~8.0 MB

    normalize_rows_i8<<<NPAD / 4, 256, 0, stream>>>(dbf, dbb, NDB, NPAD);
    normalize_rows_i8<<<NQ / 4, 256, 0, stream>>>(features, qbn, NQ, NQ);
    knn_chunk<<<NWG, 256, 0, stream>>>(qbn, dbb, partial);
    final_merge<<<NQ / 4, 256, 0, stream>>>(partial, out);
}

// Round 13
// 341.755 us; speedup vs baseline: 2.5952x; 1.1972x over previous
//
#include <hip/hip_runtime.h>
#include <hip/hip_bf16.h>

typedef unsigned short ushort_t;
typedef unsigned char uchar_t;
typedef __attribute__((ext_vector_type(4))) int int4v;
typedef __attribute__((ext_vector_type(4))) unsigned int uint4v;
typedef __attribute__((ext_vector_type(2))) unsigned int uint2v;

#define NQ      2048
#define ND      512
#define NDB     100000
#define TOPK    10
#define NCHUNK  98
#define CHUNK_N 1024                  // 8 tiles * 128
#define NPAD    (NCHUNK * CHUNK_N)    // 100352 >= 100000
#define QTILES  (NQ / 128)            // 16
#define NTILES  (CHUNK_N / 128)       // 8
#define NWG     (NCHUNK * QTILES)     // 1568 = 8 * 196
#define PERXCD  (NWG / 8)             // 196
#define QSCALE  400.0f
#define QINV    (1.0f / (QSCALE * QSCALE))
#define IMIN    (-2147483647 - 1)

// async global->LDS, 16B per lane, wave-uniform LDS base + lane*16
#define GL2LDS(gp, lp) __builtin_amdgcn_global_load_lds(                      \
    (const __attribute__((address_space(1))) void*)(gp),                     \
    (__attribute__((address_space(3))) void*)(lp), 16, 0, 0)

// ---------- row L2-normalize, fp32 -> i8 (x*400, RNE, clamp +-127); zero pad rows ----------
__global__ void normalize_rows_i8(const float* __restrict__ in, uchar_t* __restrict__ out,
                                  int nvalid, int ntotal) {
    int row  = blockIdx.x * 4 + (threadIdx.x >> 6);
    int lane = threadIdx.x & 63;
    if (row >= ntotal) return;
    uint2v pk;
    if (row >= nvalid) {
        pk[0] = 0u; pk[1] = 0u;
    } else {
        const float4* src = reinterpret_cast<const float4*>(in + (size_t)row * ND);
        float4 v0 = src[lane * 2];
        float4 v1 = src[lane * 2 + 1];
        float s = v0.x*v0.x + v0.y*v0.y + v0.z*v0.z + v0.w*v0.w
                + v1.x*v1.x + v1.y*v1.y + v1.z*v1.z + v1.w*v1.w;
        #pragma unroll
        for (int off = 32; off; off >>= 1) s += __shfl_xor(s, off, 64);
        float r = rsqrtf(s) * QSCALE;
        float f[8] = { v0.x, v0.y, v0.z, v0.w, v1.x, v1.y, v1.z, v1.w };
        unsigned b[8];
        #pragma unroll
        for (int i = 0; i < 8; ++i) {
            int q = (int)rintf(f[i] * r);
            q = q > 127 ? 127 : (q < -127 ? -127 : q);
            b[i] = (unsigned)q & 0xFFu;
        }
        pk[0] = b[0] | (b[1] << 8) | (b[2] << 16) | (b[3] << 24);
        pk[1] = b[4] | (b[5] << 8) | (b[6] << 16) | (b[7] << 24);
    }
    *reinterpret_cast<uint2v*>(out + (size_t)row * ND + lane * 8) = pk;
}

__device__ inline void topk_insert_i(int (&top)[TOPK], int x) {
    #pragma unroll
    for (int i = 0; i < TOPK; ++i) {
        int mx = top[i] > x ? top[i] : x;
        int mn = top[i] > x ? x : top[i];
        top[i] = mx;
        x = mn;
    }
}

// ---------- fused i8 GEMM + per-chunk top-10 (R12 structure, integer selection) ----------
// 256 threads, 4 waves; wave wv owns queries [wv*32, +32) x all 128 n of the tile.
// A+B staged to LDS via gl2lds (both-sides XOR swizzle; staging/frag address
// invariants hoisted, ks-loop fully unrolled so kbase folds into constants).
// Selection entirely in i32 (order-preserving): int-max prefilter, int top-10,
// int butterflies, int partial. Conversion to float happens once in final_merge.
__global__ __launch_bounds__(256, 4)
void knn_chunk(const uchar_t* __restrict__ qb, const uchar_t* __restrict__ dbb,
               int* __restrict__ partial) {
    // XCD swizzle: 16 consecutive logicals (same B-chunk) land on the same XCD
    const int logical = (blockIdx.x & 7) * PERXCD + (blockIdx.x >> 3);
    const int qt = logical & (QTILES - 1);
    const int nc = logical >> 4;       // QTILES == 16
    const int t = threadIdx.x, lane = t & 63, wv = t >> 6;

    __shared__ __align__(16) uchar_t As[128 * 128];   // 16 KB
    __shared__ __align__(16) uchar_t Bs[128 * 128];   // 16 KB

    int top[2][TOPK];
    #pragma unroll
    for (int qs = 0; qs < 2; ++qs)
        #pragma unroll
        for (int i = 0; i < TOPK; ++i) top[qs][i] = IMIN;

    const size_t nchunkbase = (size_t)nc * CHUNK_N;
    const int cb = wv * 256;                 // wave's 16B-chunk base (1024 chunks/tile)
    const uchar_t* aseg = qb + (size_t)(qt * 128) * ND;

    // ---- hoisted per-lane invariants ----
    int soff[4], doff[4];                    // staging: global row/swizzle offset, LDS dest
    #pragma unroll
    for (int i = 0; i < 4; ++i) {
        const int cid = cb + i * 64 + lane;
        const int row = cid >> 3;
        const int c   = (cid & 7) ^ (row & 7);
        soff[i] = row * ND + c * 16;
        doff[i] = cid * 16;
    }
    int abase[2], axr[2];                    // A-frag: row base, xor operand
    #pragma unroll
    for (int qs = 0; qs < 2; ++qs) {
        const int ar = wv * 32 + qs * 16 + (lane & 15);
        abase[qs] = ar * 128; axr[qs] = ar & 7;
    }
    int bbase[8], bxr[8];                    // B-frag
    #pragma unroll
    for (int ns = 0; ns < 8; ++ns) {
        const int br = ns * 16 + (lane & 15);
        bbase[ns] = br * 128; bxr[ns] = br & 7;
    }

    for (int nt = 0; nt < NTILES; ++nt) {
        const uchar_t* bseg = dbb + (nchunkbase + nt * 128) * ND;
        int4v acc[2][8];
        #pragma unroll
        for (int a = 0; a < 2; ++a)
            #pragma unroll
            for (int b = 0; b < 8; ++b)
                acc[a][b] = (int4v){0, 0, 0, 0};

        #pragma unroll
        for (int ks = 0; ks < 4; ++ks) {
            const int kbase = ks * 128;            // compile-time after unroll
            __syncthreads();   // previous sub-tile's frags consumed
            #pragma unroll
            for (int i = 0; i < 4; ++i) {
                GL2LDS(aseg + soff[i] + kbase, As + doff[i]);
                GL2LDS(bseg + soff[i] + kbase, Bs + doff[i]);
            }
            __syncthreads();   // tile staged
            #pragma unroll
            for (int ksub = 0; ksub < 2; ++ksub) {
                const int cgrp = ksub * 4 + (lane >> 4);  // logical 16B chunk in row
                int4v af[2], bf[8];
                #pragma unroll
                for (int qs = 0; qs < 2; ++qs)
                    af[qs] = *reinterpret_cast<const int4v*>(As + abase[qs] + ((cgrp ^ axr[qs]) * 16));
                #pragma unroll
                for (int ns = 0; ns < 8; ++ns)
                    bf[ns] = *reinterpret_cast<const int4v*>(Bs + bbase[ns] + ((cgrp ^ bxr[ns]) * 16));
                #pragma unroll
                for (int qs = 0; qs < 2; ++qs)
                    #pragma unroll
                    for (int ns = 0; ns < 8; ++ns)
                        acc[qs][ns] = __builtin_amdgcn_mfma_i32_16x16x64_i8(bf[ns], af[qs], acc[qs][ns], 0, 0, 0);
            }
        }

        // integer selection: per qs, 32 candidates for this thread's fixed query
        #pragma unroll
        for (int qs = 0; qs < 2; ++qs) {
            int m = acc[qs][0][0];
            #pragma unroll
            for (int ns = 0; ns < 8; ++ns)
                #pragma unroll
                for (int r = 0; r < 4; ++r)
                    m = m > acc[qs][ns][r] ? m : acc[qs][ns][r];
            if (m > top[qs][TOPK - 1]) {
                #pragma unroll
                for (int ns = 0; ns < 8; ++ns)
                    #pragma unroll
                    for (int r = 0; r < 4; ++r) {
                        int v = acc[qs][ns][r];
                        if (v > top[qs][TOPK - 1]) topk_insert_i(top[qs], v);
                    }
            }
        }
    }

    // butterfly merge across the 4 lanes sharing each query (lane ^ 16, lane ^ 32)
    #pragma unroll
    for (int qs = 0; qs < 2; ++qs) {
        #pragma unroll
        for (int step = 16; step <= 32; step <<= 1) {
            int other[TOPK];
            #pragma unroll
            for (int i = 0; i < TOPK; ++i) other[i] = __shfl_xor(top[qs][i], step, 64);
            #pragma unroll
            for (int i = 0; i < TOPK; ++i)
                if (other[i] > top[qs][TOPK - 1]) topk_insert_i(top[qs], other[i]);
        }
    }

    // lanes 0..15 hold the final per-query top-10 for q = qt*128 + wv*32 + qs*16 + lane
    if ((lane >> 4) == 0) {
        #pragma unroll
        for (int qs = 0; qs < 2; ++qs) {
            const int q = qt * 128 + wv * 32 + qs * 16 + lane;
            int* dst = partial + ((size_t)nc * NQ + q) * TOPK;
            #pragma unroll
            for (int i = 0; i < TOPK; ++i) dst[i] = top[qs][i];
        }
    }
}

// ---------- merge NCHUNK chunks per query (int domain), emit k-th squared distance ----------
__global__ void final_merge(const int* __restrict__ partial, float* __restrict__ out) {
    const int q = blockIdx.x * 4 + (threadIdx.x >> 6);
    const int lane = threadIdx.x & 63;
    if (q >= NQ) return;
    int top[TOPK];
    #pragma unroll
    for (int i = 0; i < TOPK; ++i) top[i] = IMIN;
    for (int c = lane; c < NCHUNK; c += 64) {
        const int* p = partial + ((size_t)c * NQ + q) * TOPK;
        #pragma unroll
        for (int i = 0; i < TOPK; ++i) {
            int x = p[i];
            if (x > top[TOPK - 1]) topk_insert_i(top, x);
        }
    }
    #pragma unroll
    for (int step = 1; step <= 32; step <<= 1) {
        int other[TOPK];
        #pragma unroll
        for (int i = 0; i < TOPK; ++i) other[i] = __shfl_xor(top[i], step, 64);
        #pragma unroll
        for (int i = 0; i < TOPK; ++i)
            if (other[i] > top[TOPK - 1]) topk_insert_i(top, other[i]);
    }
    if (lane == 0) out[q] = 2.0f - 2.0f * ((float)top[TOPK - 1] * QINV);
}

extern "C" void kernel_launch(void* const* d_in, const int* in_sizes, int n_in,
                              void* d_out, int out_size, void* d_ws, size_t ws_size,
                              hipStream_t stream) {
    const float* features = (const float*)d_in[0];
    const float* dbf      = (const float*)d_in[2];
    float* out = (float*)d_out;

    uchar_t* dbb = (uchar_t*)d_ws;                           // [NPAD][512] i8     ~51.4 MB
    uchar_t* qbn = dbb + (size_t)NPAD * ND;                  // [2048][512] i8     ~1 MB
    int* partial = (int*)(qbn + (size_t)NQ * ND);            // [NCHUNK][2048][10] ~8.0 MB

    normalize_rows_i8<<<NPAD / 4, 256, 0, stream>>>(dbf, dbb, NDB, NPAD);
    normalize_rows_i8<<<NQ / 4, 256, 0, stream>>>(features, qbn, NQ, NQ);
    knn_chunk<<<NWG, 256, 0, stream>>>(qbn, dbb, partial);
    final_merge<<<NQ / 4, 256, 0, stream>>>(partial, out);
}

// Round 14
// 327.098 us; speedup vs baseline: 2.7115x; 1.0448x over previous
//
#include <hip/hip_runtime.h>
#include <hip/hip_bf16.h>

typedef unsigned short ushort_t;
typedef unsigned char uchar_t;
typedef __attribute__((ext_vector_type(4))) int int4v;
typedef __attribute__((ext_vector_type(2))) unsigned int uint2v;

#define NQ      2048
#define ND      512
#define NDB     100000
#define TOPK    10
#define NCHUNK  98
#define CHUNK_N 1024                  // 8 tiles * 128
#define NPAD    (NCHUNK * CHUNK_N)    // 100352 >= 100000
#define QTILES  (NQ / 128)            // 16
#define NTILES  (CHUNK_N / 128)       // 8
#define NWG     (NCHUNK * QTILES)     // 1568 = 8 * 196
#define PERXCD  (NWG / 8)             // 196
#define QSCALE  400.0f
#define QINV    (1.0f / (QSCALE * QSCALE))
#define IMIN    (-2147483647 - 1)

// async global->LDS, 16B per lane, wave-uniform LDS base + lane*16
#define GL2LDS(gp, lp) __builtin_amdgcn_global_load_lds(                      \
    (const __attribute__((address_space(1))) void*)(gp),                     \
    (__attribute__((address_space(3))) void*)(lp), 16, 0, 0)

// ---------- row L2-normalize, fp32 -> i8 (x*400, RNE, clamp +-127); zero pad rows ----------
__global__ void normalize_rows_i8(const float* __restrict__ in, uchar_t* __restrict__ out,
                                  int nvalid, int ntotal) {
    int row  = blockIdx.x * 4 + (threadIdx.x >> 6);
    int lane = threadIdx.x & 63;
    if (row >= ntotal) return;
    uint2v pk;
    if (row >= nvalid) {
        pk[0] = 0u; pk[1] = 0u;
    } else {
        const float4* src = reinterpret_cast<const float4*>(in + (size_t)row * ND);
        float4 v0 = src[lane * 2];
        float4 v1 = src[lane * 2 + 1];
        float s = v0.x*v0.x + v0.y*v0.y + v0.z*v0.z + v0.w*v0.w
                + v1.x*v1.x + v1.y*v1.y + v1.z*v1.z + v1.w*v1.w;
        #pragma unroll
        for (int off = 32; off; off >>= 1) s += __shfl_xor(s, off, 64);
        float r = rsqrtf(s) * QSCALE;
        float f[8] = { v0.x, v0.y, v0.z, v0.w, v1.x, v1.y, v1.z, v1.w };
        unsigned b[8];
        #pragma unroll
        for (int i = 0; i < 8; ++i) {
            int q = (int)rintf(f[i] * r);
            q = q > 127 ? 127 : (q < -127 ? -127 : q);
            b[i] = (unsigned)q & 0xFFu;
        }
        pk[0] = b[0] | (b[1] << 8) | (b[2] << 16) | (b[3] << 24);
        pk[1] = b[4] | (b[5] << 8) | (b[6] << 16) | (b[7] << 24);
    }
    *reinterpret_cast<uint2v*>(out + (size_t)row * ND + lane * 8) = pk;
}

__device__ inline void topk_insert_i(int (&top)[TOPK], int x) {
    #pragma unroll
    for (int i = 0; i < TOPK; ++i) {
        int mx = top[i] > x ? top[i] : x;
        int mn = top[i] > x ? x : top[i];
        top[i] = mx;
        x = mn;
    }
}

// ---------- fused i8 GEMM + per-chunk top-10 (16 KB LDS/block -> 8 blocks/CU) ----------
// 256 threads, 4 waves; wave wv owns queries [wv*32, +32) x all 128 n of the tile.
// K-step = 64 i8 (one MFMA-K): tile 128 rows x 64 B per matrix (8 KB each).
// 64B-row swizzle (derived for <=2-way banks, free): stage col c=(cid&3)^((row>>1)&3),
// read slot cgrp^((row>>1)&3), cgrp = lane>>4. Selection all-integer (R13).
// SWAPPED mfma(B,A): acc[qs][ns][r] = dot_i32[n][q = qs*16+(lane&15)].
__global__ __launch_bounds__(256, 4)
void knn_chunk(const uchar_t* __restrict__ qb, const uchar_t* __restrict__ dbb,
               int* __restrict__ partial) {
    // XCD swizzle: 16 consecutive logicals (same B-chunk) land on the same XCD
    const int logical = (blockIdx.x & 7) * PERXCD + (blockIdx.x >> 3);
    const int qt = logical & (QTILES - 1);
    const int nc = logical >> 4;       // QTILES == 16
    const int t = threadIdx.x, lane = t & 63, wv = t >> 6;

    __shared__ __align__(16) uchar_t As[128 * 64];    // 8 KB
    __shared__ __align__(16) uchar_t Bs[128 * 64];    // 8 KB

    int top[2][TOPK];
    #pragma unroll
    for (int qs = 0; qs < 2; ++qs)
        #pragma unroll
        for (int i = 0; i < TOPK; ++i) top[qs][i] = IMIN;

    const size_t nchunkbase = (size_t)nc * CHUNK_N;
    const int cb = wv * 128;                 // wave's 16B-chunk base (512 chunks/tile)
    const uchar_t* aseg = qb + (size_t)(qt * 128) * ND;

    // ---- hoisted per-lane invariants ----
    int soff[2], doff[2];                    // staging: global offset (row + swizzled col), LDS dest
    #pragma unroll
    for (int i = 0; i < 2; ++i) {
        const int cid = cb + i * 64 + lane;
        const int row = cid >> 2;                       // 4 chunks per 64-B row
        const int c   = (cid & 3) ^ ((row >> 1) & 3);   // inverse swizzle on global source
        soff[i] = row * ND + c * 16;
        doff[i] = cid * 16;
    }
    const int cgrp = lane >> 4;              // this lane's logical 16B chunk in row
    int aoff[2];                             // A-frag LDS byte offsets (invariant)
    #pragma unroll
    for (int qs = 0; qs < 2; ++qs) {
        const int ar = wv * 32 + qs * 16 + (lane & 15);
        aoff[qs] = ar * 64 + ((cgrp ^ ((ar >> 1) & 3)) * 16);
    }
    int boff[8];                             // B-frag LDS byte offsets (invariant)
    #pragma unroll
    for (int ns = 0; ns < 8; ++ns) {
        const int br = ns * 16 + (lane & 15);
        boff[ns] = br * 64 + ((cgrp ^ ((br >> 1) & 3)) * 16);
    }

    for (int nt = 0; nt < NTILES; ++nt) {
        const uchar_t* bseg = dbb + (nchunkbase + nt * 128) * ND;
        int4v acc[2][8];
        #pragma unroll
        for (int a = 0; a < 2; ++a)
            #pragma unroll
            for (int b = 0; b < 8; ++b)
                acc[a][b] = (int4v){0, 0, 0, 0};

        #pragma unroll
        for (int ks = 0; ks < 8; ++ks) {
            const int kbase = ks * 64;             // compile-time after unroll
            __syncthreads();   // previous K-step's frags consumed
            #pragma unroll
            for (int i = 0; i < 2; ++i) {
                GL2LDS(aseg + soff[i] + kbase, As + doff[i]);
                GL2LDS(bseg + soff[i] + kbase, Bs + doff[i]);
            }
            __syncthreads();   // K-slice staged
            int4v af[2], bf[8];
            #pragma unroll
            for (int qs = 0; qs < 2; ++qs)
                af[qs] = *reinterpret_cast<const int4v*>(As + aoff[qs]);
            #pragma unroll
            for (int ns = 0; ns < 8; ++ns)
                bf[ns] = *reinterpret_cast<const int4v*>(Bs + boff[ns]);
            #pragma unroll
            for (int qs = 0; qs < 2; ++qs)
                #pragma unroll
                for (int ns = 0; ns < 8; ++ns)
                    acc[qs][ns] = __builtin_amdgcn_mfma_i32_16x16x64_i8(bf[ns], af[qs], acc[qs][ns], 0, 0, 0);
        }

        // integer selection: per qs, 32 candidates for this thread's fixed query
        #pragma unroll
        for (int qs = 0; qs < 2; ++qs) {
            int m = acc[qs][0][0];
            #pragma unroll
            for (int ns = 0; ns < 8; ++ns)
                #pragma unroll
                for (int r = 0; r < 4; ++r)
                    m = m > acc[qs][ns][r] ? m : acc[qs][ns][r];
            if (m > top[qs][TOPK - 1]) {
                #pragma unroll
                for (int ns = 0; ns < 8; ++ns)
                    #pragma unroll
                    for (int r = 0; r < 4; ++r) {
                        int v = acc[qs][ns][r];
                        if (v > top[qs][TOPK - 1]) topk_insert_i(top[qs], v);
                    }
            }
        }
    }

    // butterfly merge across the 4 lanes sharing each query (lane ^ 16, lane ^ 32)
    #pragma unroll
    for (int qs = 0; qs < 2; ++qs) {
        #pragma unroll
        for (int step = 16; step <= 32; step <<= 1) {
            int other[TOPK];
            #pragma unroll
            for (int i = 0; i < TOPK; ++i) other[i] = __shfl_xor(top[qs][i], step, 64);
            #pragma unroll
            for (int i = 0; i < TOPK; ++i)
                if (other[i] > top[qs][TOPK - 1]) topk_insert_i(top[qs], other[i]);
        }
    }

    // lanes 0..15 hold the final per-query top-10 for q = qt*128 + wv*32 + qs*16 + lane
    if ((lane >> 4) == 0) {
        #pragma unroll
        for (int qs = 0; qs < 2; ++qs) {
            const int q = qt * 128 + wv * 32 + qs * 16 + lane;
            int* dst = partial + ((size_t)nc * NQ + q) * TOPK;
            #pragma unroll
            for (int i = 0; i < TOPK; ++i) dst[i] = top[qs][i];
        }
    }
}

// ---------- merge NCHUNK chunks per query (int domain), emit k-th squared distance ----------
__global__ void final_merge(const int* __restrict__ partial, float* __restrict__ out) {
    const int q = blockIdx.x * 4 + (threadIdx.x >> 6);
    const int lane = threadIdx.x & 63;
    if (q >= NQ) return;
    int top[TOPK];
    #pragma unroll
    for (int i = 0; i < TOPK; ++i) top[i] = IMIN;
    for (int c = lane; c < NCHUNK; c += 64) {
        const int* p = partial + ((size_t)c * NQ + q) * TOPK;
        #pragma unroll
        for (int i = 0; i < TOPK; ++i) {
            int x = p[i];
            if (x > top[TOPK - 1]) topk_insert_i(top, x);
        }
    }
    #pragma unroll
    for (int step = 1; step <= 32; step <<= 1) {
        int other[TOPK];
        #pragma unroll
        for (int i = 0; i < TOPK; ++i) other[i] = __shfl_xor(top[i], step, 64);
        #pragma unroll
        for (int i = 0; i < TOPK; ++i)
            if (other[i] > top[TOPK - 1]) topk_insert_i(top, other[i]);
    }
    if (lane == 0) out[q] = 2.0f - 2.0f * ((float)top[TOPK - 1] * QINV);
}

extern "C" void kernel_launch(void* const* d_in, const int* in_sizes, int n_in,
                              void* d_out, int out_size, void* d_ws, size_t ws_size,
                              hipStream_t stream) {
    const float* features = (const float*)d_in[0];
    const float* dbf      = (const float*)d_in[2];
    float* out = (float*)d_out;

    uchar_t* dbb = (uchar_t*)d_ws;                           // [NPAD][512] i8     ~51.4 MB
    uchar_t* qbn = dbb + (size_t)NPAD * ND;                  // [2048][512] i8     ~1 MB
    int* partial = (int*)(qbn + (size_t)NQ * ND);            // [NCHUNK][2048][10] ~8.0 MB

    normalize_rows_i8<<<NPAD / 4, 256, 0, stream>>>(dbf, dbb, NDB, NPAD);
    normalize_rows_i8<<<NQ / 4, 256, 0, stream>>>(features, qbn, NQ, NQ);
    knn_chunk<<<NWG, 256, 0, stream>>>(qbn, dbb, partial);
    final_merge<<<NQ / 4, 256, 0, stream>>>(partial, out);
}

// Round 15
// 301.613 us; speedup vs baseline: 2.9406x; 1.0845x over previous
//
#include <hip/hip_runtime.h>
#include <hip/hip_bf16.h>

typedef unsigned short ushort_t;
typedef unsigned char uchar_t;
typedef __attribute__((ext_vector_type(4))) int int4v;
typedef __attribute__((ext_vector_type(2))) unsigned int uint2v;

#define NQ      2048
#define ND      512
#define NDB     100000
#define TOPK    10
#define NCHUNK  98
#define CHUNK_N 1024                  // 8 tiles * 128
#define NPAD    (NCHUNK * CHUNK_N)    // 100352 >= 100000
#define QTILES  (NQ / 128)            // 16
#define NTILES  (CHUNK_N / 128)       // 8
#define NWG     (NCHUNK * QTILES)     // 1568 = 8 * 196
#define PERXCD  (NWG / 8)             // 196
#define QSCALE  400.0f
#define QINV    (1.0f / (QSCALE * QSCALE))
#define IMIN    (-2147483647 - 1)

// async global->LDS, 16B per lane, wave-uniform LDS base + lane*16
#define GL2LDS(gp, lp) __builtin_amdgcn_global_load_lds(                      \
    (const __attribute__((address_space(1))) void*)(gp),                     \
    (__attribute__((address_space(3))) void*)(lp), 16, 0, 0)

// ---------- row L2-normalize, fp32 -> i8 (x*400, RNE, clamp +-127); zero pad rows ----------
__global__ void normalize_rows_i8(const float* __restrict__ in, uchar_t* __restrict__ out,
                                  int nvalid, int ntotal) {
    int row  = blockIdx.x * 4 + (threadIdx.x >> 6);
    int lane = threadIdx.x & 63;
    if (row >= ntotal) return;
    uint2v pk;
    if (row >= nvalid) {
        pk[0] = 0u; pk[1] = 0u;
    } else {
        const float4* src = reinterpret_cast<const float4*>(in + (size_t)row * ND);
        float4 v0 = src[lane * 2];
        float4 v1 = src[lane * 2 + 1];
        float s = v0.x*v0.x + v0.y*v0.y + v0.z*v0.z + v0.w*v0.w
                + v1.x*v1.x + v1.y*v1.y + v1.z*v1.z + v1.w*v1.w;
        #pragma unroll
        for (int off = 32; off; off >>= 1) s += __shfl_xor(s, off, 64);
        float r = rsqrtf(s) * QSCALE;
        float f[8] = { v0.x, v0.y, v0.z, v0.w, v1.x, v1.y, v1.z, v1.w };
        unsigned b[8];
        #pragma unroll
        for (int i = 0; i < 8; ++i) {
            int q = (int)rintf(f[i] * r);
            q = q > 127 ? 127 : (q < -127 ? -127 : q);
            b[i] = (unsigned)q & 0xFFu;
        }
        pk[0] = b[0] | (b[1] << 8) | (b[2] << 16) | (b[3] << 24);
        pk[1] = b[4] | (b[5] << 8) | (b[6] << 16) | (b[7] << 24);
    }
    *reinterpret_cast<uint2v*>(out + (size_t)row * ND + lane * 8) = pk;
}

__device__ inline void topk_insert_i(int (&top)[TOPK], int x) {
    #pragma unroll
    for (int i = 0; i < TOPK; ++i) {
        int mx = top[i] > x ? top[i] : x;
        int mn = top[i] > x ? x : top[i];
        top[i] = mx;
        x = mn;
    }
}

// ---------- fused i8 GEMM + per-chunk top-10: 8 waves x 16q, 64-VGPR budget ----------
// 512 threads, 8 waves; wave wv owns queries [wv*16, +16) x all 128 n of the tile.
// Same 128x64B tiles + swizzle as R14. Key VGPR economy: acc[8] (32 regs, one
// q-row), single af, bf in two groups of 4, frag addresses = ONE base VGPR +
// compile-time immediate offsets (swizzle term (row>>1)&3 depends only on l15,
// so row base ns*1024 folds into ds_read offset:). Target: 64 VGPR -> 8 waves/SIMD,
// 4 blocks/CU = 32 waves/CU.
__global__ __launch_bounds__(512, 8)
void knn_chunk(const uchar_t* __restrict__ qb, const uchar_t* __restrict__ dbb,
               int* __restrict__ partial) {
    // XCD swizzle: 16 consecutive logicals (same B-chunk) land on the same XCD
    const int logical = (blockIdx.x & 7) * PERXCD + (blockIdx.x >> 3);
    const int qt = logical & (QTILES - 1);
    const int nc = logical >> 4;       // QTILES == 16
    const int t = threadIdx.x, lane = t & 63, wv = t >> 6;
    const int l15 = lane & 15;

    __shared__ __align__(16) uchar_t As[128 * 64];    // 8 KB
    __shared__ __align__(16) uchar_t Bs[128 * 64];    // 8 KB

    int top[TOPK];
    #pragma unroll
    for (int i = 0; i < TOPK; ++i) top[i] = IMIN;

    const size_t nchunkbase = (size_t)nc * CHUNK_N;
    const uchar_t* aseg = qb + (size_t)(qt * 128) * ND;

    // ---- hoisted per-lane invariants ----
    // staging: thread t covers chunk t of each matrix (512 chunks = 128 rows x 4)
    const int srow = t >> 2;
    const int scol = (t & 3) ^ ((srow >> 1) & 3);       // inverse swizzle on global source
    const int soff = srow * ND + scol * 16;
    const int doff = t * 16;
    // frag reads: swizzle slot depends only on l15 -> one base + imm offsets
    const int cgrp = lane >> 4;                          // logical 16B chunk in row
    const int slot = (cgrp ^ ((l15 >> 1) & 3)) * 16;
    const int aoff = (wv * 16 + l15) * 64 + slot;        // A row = wv*16 + l15
    const int boff = l15 * 64 + slot;                    // B row = ns*16 + l15 (ns via imm)

    for (int nt = 0; nt < NTILES; ++nt) {
        const uchar_t* bseg = dbb + (nchunkbase + nt * 128) * ND;
        int4v acc[8];
        #pragma unroll
        for (int b = 0; b < 8; ++b) acc[b] = (int4v){0, 0, 0, 0};

        #pragma unroll
        for (int ks = 0; ks < 8; ++ks) {
            const int kbase = ks * 64;             // compile-time after unroll
            __syncthreads();   // previous K-step's frags consumed
            GL2LDS(aseg + soff + kbase, As + doff);
            GL2LDS(bseg + soff + kbase, Bs + doff);
            __syncthreads();   // K-slice staged (implicit vmcnt(0))
            int4v af = *reinterpret_cast<const int4v*>(As + aoff);
            // two groups of 4 to cap live bf regs at 16
            {
                int4v bf0 = *reinterpret_cast<const int4v*>(Bs + boff);
                int4v bf1 = *reinterpret_cast<const int4v*>(Bs + boff + 1024);
                int4v bf2 = *reinterpret_cast<const int4v*>(Bs + boff + 2048);
                int4v bf3 = *reinterpret_cast<const int4v*>(Bs + boff + 3072);
                acc[0] = __builtin_amdgcn_mfma_i32_16x16x64_i8(bf0, af, acc[0], 0, 0, 0);
                acc[1] = __builtin_amdgcn_mfma_i32_16x16x64_i8(bf1, af, acc[1], 0, 0, 0);
                acc[2] = __builtin_amdgcn_mfma_i32_16x16x64_i8(bf2, af, acc[2], 0, 0, 0);
                acc[3] = __builtin_amdgcn_mfma_i32_16x16x64_i8(bf3, af, acc[3], 0, 0, 0);
            }
            {
                int4v bf4 = *reinterpret_cast<const int4v*>(Bs + boff + 4096);
                int4v bf5 = *reinterpret_cast<const int4v*>(Bs + boff + 5120);
                int4v bf6 = *reinterpret_cast<const int4v*>(Bs + boff + 6144);
                int4v bf7 = *reinterpret_cast<const int4v*>(Bs + boff + 7168);
                acc[4] = __builtin_amdgcn_mfma_i32_16x16x64_i8(bf4, af, acc[4], 0, 0, 0);
                acc[5] = __builtin_amdgcn_mfma_i32_16x16x64_i8(bf5, af, acc[5], 0, 0, 0);
                acc[6] = __builtin_amdgcn_mfma_i32_16x16x64_i8(bf6, af, acc[6], 0, 0, 0);
                acc[7] = __builtin_amdgcn_mfma_i32_16x16x64_i8(bf7, af, acc[7], 0, 0, 0);
            }
        }

        // integer selection: 32 candidates for this thread's single query
        int m = acc[0][0];
        #pragma unroll
        for (int ns = 0; ns < 8; ++ns)
            #pragma unroll
            for (int r = 0; r < 4; ++r)
                m = m > acc[ns][r] ? m : acc[ns][r];
        if (m > top[TOPK - 1]) {
            #pragma unroll
            for (int ns = 0; ns < 8; ++ns)
                #pragma unroll
                for (int r = 0; r < 4; ++r) {
                    int v = acc[ns][r];
                    if (v > top[TOPK - 1]) topk_insert_i(top, v);
                }
        }
    }

    // butterfly merge across the 4 lanes sharing each query (lane ^ 16, lane ^ 32)
    #pragma unroll
    for (int step = 16; step <= 32; step <<= 1) {
        int other[TOPK];
        #pragma unroll
        for (int i = 0; i < TOPK; ++i) other[i] = __shfl_xor(top[i], step, 64);
        #pragma unroll
        for (int i = 0; i < TOPK; ++i)
            if (other[i] > top[TOPK - 1]) topk_insert_i(top, other[i]);
    }

    // lanes 0..15 hold the final per-query top-10 for q = qt*128 + wv*16 + l15
    if ((lane >> 4) == 0) {
        const int q = qt * 128 + wv * 16 + l15;
        int* dst = partial + ((size_t)nc * NQ + q) * TOPK;
        #pragma unroll
        for (int i = 0; i < TOPK; ++i) dst[i] = top[i];
    }
}

// ---------- merge NCHUNK chunks per query (int domain), emit k-th squared distance ----------
__global__ void final_merge(const int* __restrict__ partial, float* __restrict__ out) {
    const int q = blockIdx.x * 4 + (threadIdx.x >> 6);
    const int lane = threadIdx.x & 63;
    if (q >= NQ) return;
    int top[TOPK];
    #pragma unroll
    for (int i = 0; i < TOPK; ++i) top[i] = IMIN;
    for (int c = lane; c < NCHUNK; c += 64) {
        const int* p = partial + ((size_t)c * NQ + q) * TOPK;
        #pragma unroll
        for (int i = 0; i < TOPK; ++i) {
            int x = p[i];
            if (x > top[TOPK - 1]) topk_insert_i(top, x);
        }
    }
    #pragma unroll
    for (int step = 1; step <= 32; step <<= 1) {
        int other[TOPK];
        #pragma unroll
        for (int i = 0; i < TOPK; ++i) other[i] = __shfl_xor(top[i], step, 64);
        #pragma unroll
        for (int i = 0; i < TOPK; ++i)
            if (other[i] > top[TOPK - 1]) topk_insert_i(top, other[i]);
    }
    if (lane == 0) out[q] = 2.0f - 2.0f * ((float)top[TOPK - 1] * QINV);
}

extern "C" void kernel_launch(void* const* d_in, const int* in_sizes, int n_in,
                              void* d_out, int out_size, void* d_ws, size_t ws_size,
                              hipStream_t stream) {
    const float* features = (const float*)d_in[0];
    const float* dbf      = (const float*)d_in[2];
    float* out = (float*)d_out;

    uchar_t* dbb = (uchar_t*)d_ws;                           // [NPAD][512] i8     ~51.4 MB
    uchar_t* qbn = dbb + (size_t)NPAD * ND;                  // [2048][512] i8     ~1 MB
    int* partial = (int*)(qbn + (size_t)NQ * ND);            // [NCHUNK][2048][10] ~8.0 MB

    normalize_rows_i8<<<NPAD / 4, 256, 0, stream>>>(dbf, dbb, NDB, NPAD);
    normalize_rows_i8<<<NQ / 4, 256, 0, stream>>>(features, qbn, NQ, NQ);
    knn_chunk<<<NWG, 512, 0, stream>>>(qbn, dbb, partial);
    final_merge<<<NQ / 4, 256, 0, stream>>>(partial, out);
}